// Round 5
// baseline (92.924 us; speedup 1.0000x reference)
//
#include <hip/hip_runtime.h>

// Fused Swin shifted-window MSA, one workgroup (4 waves) per 7x7 window.
// Round 5: latency attack — zero-LDS QKV. Each wave computes ITS OWN head's
// Q,K,V via MFMA and redistributes D->frag layouts entirely in registers
// (same shuffle template as round-4's V path, re-derived for Q/K: pair-select
// over the d-tile by hiSel, same srcA/srcB word mapping). 3 barriers -> 1,
// LDS 33.8KB -> 17.4KB (O exchange for cross-head out-proj only).

#define HWD 56
#define SCALE_Q 0.17677669529663687f   // 1/sqrt(32)

typedef _Float16 f16x8 __attribute__((ext_vector_type(8)));
typedef __fp16   h16x2 __attribute__((ext_vector_type(2)));   // cvt_pkrtz return type
typedef float    f32x4 __attribute__((ext_vector_type(4)));

__device__ __forceinline__ unsigned pkrtz(float a, float b) {
    union { h16x2 h; unsigned u; } r;
    r.h = __builtin_amdgcn_cvt_pkrtz(a, b);
    return r.u;
}

__device__ __forceinline__ f32x4 mfma16(const unsigned a[4], const unsigned b[4], f32x4 c) {
    union { unsigned u[4]; f16x8 h; } A, B;
    A.u[0] = a[0]; A.u[1] = a[1]; A.u[2] = a[2]; A.u[3] = a[3];
    B.u[0] = b[0]; B.u[1] = b[1]; B.u[2] = b[2]; B.u[3] = b[3];
    return __builtin_amdgcn_mfma_f32_16x16x32_f16(A.h, B.h, c, 0, 0, 0);
}

__device__ __forceinline__ unsigned short f16b(float v) {
    union { _Float16 h; unsigned short s; } cv; cv.h = (_Float16)v; return cv.s;
}

// whQKV: f16 [384][128] (rows 0..127 pre-scaled by 1/sqrt(hd))
// whP  : f16 [128][128]
// biasT: f32 [wtype][head][i][j]  (rel-pos bias + shift mask + key-pad mask)
__global__ void prep2(const float* __restrict__ rpb,
                      const float* __restrict__ w_qkv,
                      const float* __restrict__ w_proj,
                      unsigned short* __restrict__ whQKV,
                      unsigned short* __restrict__ whP,
                      float* __restrict__ biasT)
{
    int idx = blockIdx.x * 256 + threadIdx.x;               // 131072 total
    if (idx < 49152) {
        float v = w_qkv[idx];
        if (idx < 16384) v *= SCALE_Q;                      // q rows 0..127
        whQKV[idx] = f16b(v);
    } else if (idx < 65536) {
        int j = idx - 49152;
        whP[j] = f16b(w_proj[j]);
    } else {
        int k = idx - 65536;                                // 65536 bias elems
        int j = k & 63, i = (k >> 6) & 63, h = (k >> 12) & 3, t = k >> 14;
        float v;
        if (j >= 49)      v = -1e30f;                       // key padding
        else if (i >= 49) v = 0.f;                          // query padding (don't care)
        else {
            int ri = i / 7, ci = i % 7, rj = j / 7, cj = j % 7;
            int rel = (ri - rj + 6) * 13 + (ci - cj + 6);
            v = rpb[rel * 4 + h];
            int gi = ((t & 2) ? (ri < 4 ? 1 : 2) : 0) * 3 + ((t & 1) ? (ci < 4 ? 1 : 2) : 0);
            int gj = ((t & 2) ? (rj < 4 ? 1 : 2) : 0) * 3 + ((t & 1) ? (cj < 4 ? 1 : 2) : 0);
            if (gi != gj) v -= 100.f;
        }
        biasT[k] = v;
    }
}

__global__ __launch_bounds__(256, 4)
void swin_msa_mfma3(const float* __restrict__ x,
                    const unsigned short* __restrict__ whQKV,
                    const unsigned short* __restrict__ whP,
                    const float* __restrict__ b_proj,
                    const float* __restrict__ biasT,
                    float* __restrict__ out)
{
    // Only O crosses waves (out-proj mixes all heads' d): 64 x 136 halves.
    __shared__ __align__(16) unsigned short Osh[64 * 136];   // 17408 B

    const int tid  = threadIdx.x;
    const int h    = tid >> 6;         // wave id == head
    const int lane = tid & 63;
    const int c    = lane & 15;
    const int g    = lane >> 4;

    const int blk  = blockIdx.x;
    const int b    = blk >> 6;
    const int wIdx = blk & 63;
    const int wh   = wIdx >> 3, ww = wIdx & 7;
    const int wtype = ((wh == 7) ? 2 : 0) | ((ww == 7) ? 1 : 0);

    auto tokAddr = [&](int tok) {      // tok must be < 49
        int rr = tok / 7, cc = tok - rr * 7;
        int sh = wh * 7 + rr + 3; if (sh >= HWD) sh -= HWD;
        int sw = ww * 7 + cc + 3; if (sw >= HWD) sw -= HWD;
        return ((b * HWD + sh) * HWD + sw) * 128;
    };

    // ---- X fragments (A- and B-frag layouts identical for X)
    unsigned xf[4][4][4];              // [tok-tile][kstep][word]
    #pragma unroll
    for (int nt = 0; nt < 4; ++nt) {
        int tok = nt * 16 + c; if (tok > 48) tok = 48;      // clamp pad rows
        const float* xr = x + tokAddr(tok) + g * 8;
        #pragma unroll
        for (int kk = 0; kk < 4; ++kk) {
            float4 lo = *(const float4*)(xr + kk * 32);
            float4 hi = *(const float4*)(xr + kk * 32 + 4);
            xf[nt][kk][0] = pkrtz(lo.x, lo.y);
            xf[nt][kk][1] = pkrtz(lo.z, lo.w);
            xf[nt][kk][2] = pkrtz(hi.x, hi.y);
            xf[nt][kk][3] = pkrtz(hi.z, hi.w);
        }
    }

    const int srcA  = c | ((lane & 16) << 1);  // lane (c, 2*(g&1))
    const int srcB  = srcA + 16;               // lane (c, 2*(g&1)+1)
    const bool hiSel = (lane & 32) != 0;       // g>>1 selects the tile-pair member

    // D->frag redistribution template (verified in round 4 for V/P paths):
    // f[p] from srcA word p of pair[hiSel], f[2+p] from srcB word p.
    auto redist = [&](const unsigned pkLo[2], const unsigned pkHi[2], unsigned f[4]) {
        #pragma unroll
        for (int p = 0; p < 2; ++p) {
            unsigned lo0 = __shfl(pkLo[p], srcA);
            unsigned hi0 = __shfl(pkHi[p], srcA);
            f[p] = hiSel ? hi0 : lo0;
            unsigned lo1 = __shfl(pkLo[p], srcB);
            unsigned hi1 = __shfl(pkHi[p], srcB);
            f[2 + p] = hiSel ? hi1 : lo1;
        }
    };

    // ================= phase A: own-head Q,K,V (no LDS, no barrier) ========
    unsigned qB[4][4];                 // B[k=d][n=i] per i-tile nt
    unsigned kA[4][4];                 // A[m=j][k=d] per j-tile mt
    unsigned vA[2][2][4];              // A[m=d][k=j] per (d-tile dn, j-chunk kv)
    {
        unsigned pkP[2][4][2];         // [d-tile][tok-tile][word], reused Q then K
        // --- Q: weight rows 32h + 16ql + c (pre-scaled); mfma(Wq, X) -> D[qcol][tok]
        #pragma unroll
        for (int ql = 0; ql < 2; ++ql) {
            unsigned af[4][4];
            const unsigned short* wr = whQKV + (32 * h + 16 * ql + c) * 128 + g * 8;
            #pragma unroll
            for (int kk = 0; kk < 4; ++kk) {
                uint4 v = *(const uint4*)(wr + kk * 32);
                af[kk][0] = v.x; af[kk][1] = v.y; af[kk][2] = v.z; af[kk][3] = v.w;
            }
            #pragma unroll
            for (int nt = 0; nt < 4; ++nt) {
                f32x4 acc = {0.f, 0.f, 0.f, 0.f};
                #pragma unroll
                for (int kk = 0; kk < 4; ++kk) acc = mfma16(af[kk], xf[nt][kk], acc);
                pkP[ql][nt][0] = pkrtz(acc[0], acc[1]);
                pkP[ql][nt][1] = pkrtz(acc[2], acc[3]);
            }
        }
        #pragma unroll
        for (int nt = 0; nt < 4; ++nt) redist(pkP[0][nt], pkP[1][nt], qB[nt]);

        // --- K: weight rows 128 + 32h + 16kl + c; mfma(Wk, X) -> D[kcol][tok]
        #pragma unroll
        for (int kl = 0; kl < 2; ++kl) {
            unsigned af[4][4];
            const unsigned short* wr = whQKV + (128 + 32 * h + 16 * kl + c) * 128 + g * 8;
            #pragma unroll
            for (int kk = 0; kk < 4; ++kk) {
                uint4 v = *(const uint4*)(wr + kk * 32);
                af[kk][0] = v.x; af[kk][1] = v.y; af[kk][2] = v.z; af[kk][3] = v.w;
            }
            #pragma unroll
            for (int mt = 0; mt < 4; ++mt) {
                f32x4 acc = {0.f, 0.f, 0.f, 0.f};
                #pragma unroll
                for (int kk = 0; kk < 4; ++kk) acc = mfma16(af[kk], xf[mt][kk], acc);
                pkP[kl][mt][0] = pkrtz(acc[0], acc[1]);
                pkP[kl][mt][1] = pkrtz(acc[2], acc[3]);
            }
        }
        #pragma unroll
        for (int mt = 0; mt < 4; ++mt) redist(pkP[0][mt], pkP[1][mt], kA[mt]);

        // --- V: weight rows 256 + 32h + 16vl + c; mfma(X, Wv) -> D[tok][d]
        unsigned pkV[2][4][2];         // [vl][tok-tile][word]
        #pragma unroll
        for (int vl = 0; vl < 2; ++vl) {
            unsigned bf[4][4];
            const unsigned short* wr = whQKV + (256 + 32 * h + 16 * vl + c) * 128 + g * 8;
            #pragma unroll
            for (int kk = 0; kk < 4; ++kk) {
                uint4 v = *(const uint4*)(wr + kk * 32);
                bf[kk][0] = v.x; bf[kk][1] = v.y; bf[kk][2] = v.z; bf[kk][3] = v.w;
            }
            #pragma unroll
            for (int mt = 0; mt < 4; ++mt) {
                f32x4 acc = {0.f, 0.f, 0.f, 0.f};
                #pragma unroll
                for (int kk = 0; kk < 4; ++kk) acc = mfma16(xf[mt][kk], bf[kk], acc);
                pkV[vl][mt][0] = pkrtz(acc[0], acc[1]);
                pkV[vl][mt][1] = pkrtz(acc[2], acc[3]);
            }
        }
        #pragma unroll
        for (int vl = 0; vl < 2; ++vl)
            #pragma unroll
            for (int kv = 0; kv < 2; ++kv)
                redist(pkV[vl][2 * kv], pkV[vl][2 * kv + 1], vA[vl][kv]);
    }

    // ================= attention (all in-register, per-i-tile fused) =======
    const float* bT = biasT + (wtype * 4 + h) * 4096;       // [i][j]
    f32x4 O[4][2];
    #pragma unroll
    for (int nt = 0; nt < 4; ++nt) {
        O[nt][0] = (f32x4){0.f, 0.f, 0.f, 0.f};
        O[nt][1] = (f32x4){0.f, 0.f, 0.f, 0.f};
    }

    #pragma unroll
    for (int nt = 0; nt < 4; ++nt) {
        f32x4 S[4];                    // S^T: lane j=16mt+4g+r, i=16nt+c
        #pragma unroll
        for (int mt = 0; mt < 4; ++mt) {
            float4 b4 = *(const float4*)&bT[(nt * 16 + c) * 64 + mt * 16 + 4 * g];
            f32x4 C = { b4.x, b4.y, b4.z, b4.w };           // bias as MFMA C-operand
            S[mt] = mfma16(kA[mt], qB[nt], C);
        }
        // softmax over j (16 in-lane + 2 butterflies)
        float m = -1e30f;
        #pragma unroll
        for (int mt = 0; mt < 4; ++mt)
            #pragma unroll
            for (int r = 0; r < 4; ++r) m = fmaxf(m, S[mt][r]);
        m = fmaxf(m, __shfl_xor(m, 16));
        m = fmaxf(m, __shfl_xor(m, 32));
        float s = 0.f;
        #pragma unroll
        for (int mt = 0; mt < 4; ++mt)
            #pragma unroll
            for (int r = 0; r < 4; ++r) { float e = __expf(S[mt][r] - m); S[mt][r] = e; s += e; }
        s += __shfl_xor(s, 16);
        s += __shfl_xor(s, 32);
        const float iv = 1.0f / s;
        // P -> B-frag via shuffles, PV mfma
        unsigned pk[4][2];
        #pragma unroll
        for (int mt = 0; mt < 4; ++mt) {
            pk[mt][0] = pkrtz(S[mt][0] * iv, S[mt][1] * iv);
            pk[mt][1] = pkrtz(S[mt][2] * iv, S[mt][3] * iv);
        }
        #pragma unroll
        for (int kk = 0; kk < 2; ++kk) {
            unsigned pB[4];
            redist(pk[2 * kk], pk[2 * kk + 1], pB);
            #pragma unroll
            for (int dn = 0; dn < 2; ++dn)
                O[nt][dn] = mfma16(vA[dn][kk], pB, O[nt][dn]);
        }
    }

    // O -> LDS: lane i = nt*16+c, d = 32h + 16dn + 4g..+3, stride 136 halves
    #pragma unroll
    for (int nt = 0; nt < 4; ++nt)
        #pragma unroll
        for (int dn = 0; dn < 2; ++dn)
            *(uint2*)&Osh[(nt * 16 + c) * 136 + 32 * h + 16 * dn + 4 * g] =
                make_uint2(pkrtz(O[nt][dn][0], O[nt][dn][1]),
                           pkrtz(O[nt][dn][2], O[nt][dn][3]));
    __syncthreads();                   // the kernel's ONLY barrier

    // ================= out-proj: OUT = O @ Wproj^T + b =================
    int taddr[4];
    #pragma unroll
    for (int nt = 0; nt < 4; ++nt) {
        int tok = nt * 16 + c;
        taddr[nt] = (tok < 49) ? tokAddr(tok) : -1;
    }
    unsigned oB[4][4][4];              // B[k=d][n=i] from O[i][d]
    #pragma unroll
    for (int nt = 0; nt < 4; ++nt)
        #pragma unroll
        for (int kk = 0; kk < 4; ++kk) {
            uint4 v = *(const uint4*)&Osh[(nt * 16 + c) * 136 + kk * 32 + g * 8];
            oB[nt][kk][0] = v.x; oB[nt][kk][1] = v.y; oB[nt][kk][2] = v.z; oB[nt][kk][3] = v.w;
        }
    #pragma unroll
    for (int mi = 0; mi < 2; ++mi) {
        const int mt = 2 * h + mi;                          // out-col tile 0..7
        unsigned aW[4][4];
        const unsigned short* wr = whP + (mt * 16 + c) * 128 + g * 8;
        #pragma unroll
        for (int kk = 0; kk < 4; ++kk) {
            uint4 v = *(const uint4*)(wr + kk * 32);
            aW[kk][0] = v.x; aW[kk][1] = v.y; aW[kk][2] = v.z; aW[kk][3] = v.w;
        }
        float4 bias4 = *(const float4*)(b_proj + mt * 16 + 4 * g);
        #pragma unroll
        for (int nt = 0; nt < 4; ++nt) {
            f32x4 acc = {0.f, 0.f, 0.f, 0.f};
            #pragma unroll
            for (int kk = 0; kk < 4; ++kk) acc = mfma16(aW[kk], oB[nt][kk], acc);
            if (taddr[nt] >= 0) {
                float4 o = make_float4(acc[0] + bias4.x, acc[1] + bias4.y,
                                       acc[2] + bias4.z, acc[3] + bias4.w);
                *(float4*)(out + taddr[nt] + mt * 16 + 4 * g) = o;
            }
        }
    }
}

extern "C" void kernel_launch(void* const* d_in, const int* in_sizes, int n_in,
                              void* d_out, int out_size, void* d_ws, size_t ws_size,
                              hipStream_t stream) {
    const float* x     = (const float*)d_in[0];
    const float* rpb   = (const float*)d_in[1];
    const float* wqkv  = (const float*)d_in[2];
    const float* wproj = (const float*)d_in[3];
    const float* bproj = (const float*)d_in[4];
    float* outp = (float*)d_out;

    unsigned short* whQKV = (unsigned short*)d_ws;          // 49152 halves
    unsigned short* whP   = whQKV + 49152;                  // 16384 halves
    float* biasT = (float*)(whP + 16384);                   // 65536 f32

    prep2<<<512, 256, 0, stream>>>(rpb, wqkv, wproj, whQKV, whP, biasT);
    swin_msa_mfma3<<<32 * 64, 256, 0, stream>>>(x, whQKV, whP, bproj, biasT, outp);
}

// Round 6
// 76.123 us; speedup vs baseline: 1.2207x; 1.2207x over previous
//
#include <hip/hip_runtime.h>

// Fused Swin shifted-window MSA, one workgroup (4 waves) per 7x7 window.
// Round 6: round-5 structure (per-wave own-head QKV, in-register redist,
// zero cross-wave traffic until O) but X fragments staged in LDS instead of
// 64 persistent VGPRs -> no scratch spills (round 5 wrote 119MB vs 51MB out).
// X: coalesced f32 load -> f16 LDS [64][136]; pad rows zero-filled (bias
// table masks pad keys, P(pad)=0 kills pad V rows). 2 barriers total.

#define HWD 56
#define SCALE_Q 0.17677669529663687f   // 1/sqrt(32)

typedef _Float16 f16x8 __attribute__((ext_vector_type(8)));
typedef __fp16   h16x2 __attribute__((ext_vector_type(2)));   // cvt_pkrtz return type
typedef float    f32x4 __attribute__((ext_vector_type(4)));

__device__ __forceinline__ unsigned pkrtz(float a, float b) {
    union { h16x2 h; unsigned u; } r;
    r.h = __builtin_amdgcn_cvt_pkrtz(a, b);
    return r.u;
}

__device__ __forceinline__ f32x4 mfma16(const unsigned a[4], const unsigned b[4], f32x4 c) {
    union { unsigned u[4]; f16x8 h; } A, B;
    A.u[0] = a[0]; A.u[1] = a[1]; A.u[2] = a[2]; A.u[3] = a[3];
    B.u[0] = b[0]; B.u[1] = b[1]; B.u[2] = b[2]; B.u[3] = b[3];
    return __builtin_amdgcn_mfma_f32_16x16x32_f16(A.h, B.h, c, 0, 0, 0);
}

__device__ __forceinline__ unsigned short f16b(float v) {
    union { _Float16 h; unsigned short s; } cv; cv.h = (_Float16)v; return cv.s;
}

// whQKV: f16 [384][128] (rows 0..127 pre-scaled by 1/sqrt(hd))
// whP  : f16 [128][128]
// biasT: f32 [wtype][head][i][j]  (rel-pos bias + shift mask + key-pad mask)
__global__ void prep2(const float* __restrict__ rpb,
                      const float* __restrict__ w_qkv,
                      const float* __restrict__ w_proj,
                      unsigned short* __restrict__ whQKV,
                      unsigned short* __restrict__ whP,
                      float* __restrict__ biasT)
{
    int idx = blockIdx.x * 256 + threadIdx.x;               // 131072 total
    if (idx < 49152) {
        float v = w_qkv[idx];
        if (idx < 16384) v *= SCALE_Q;                      // q rows 0..127
        whQKV[idx] = f16b(v);
    } else if (idx < 65536) {
        int j = idx - 49152;
        whP[j] = f16b(w_proj[j]);
    } else {
        int k = idx - 65536;                                // 65536 bias elems
        int j = k & 63, i = (k >> 6) & 63, h = (k >> 12) & 3, t = k >> 14;
        float v;
        if (j >= 49)      v = -1e30f;                       // key padding
        else if (i >= 49) v = 0.f;                          // query padding (don't care)
        else {
            int ri = i / 7, ci = i % 7, rj = j / 7, cj = j % 7;
            int rel = (ri - rj + 6) * 13 + (ci - cj + 6);
            v = rpb[rel * 4 + h];
            int gi = ((t & 2) ? (ri < 4 ? 1 : 2) : 0) * 3 + ((t & 1) ? (ci < 4 ? 1 : 2) : 0);
            int gj = ((t & 2) ? (rj < 4 ? 1 : 2) : 0) * 3 + ((t & 1) ? (cj < 4 ? 1 : 2) : 0);
            if (gi != gj) v -= 100.f;
        }
        biasT[k] = v;
    }
}

__global__ __launch_bounds__(256, 4)
void swin_msa_mfma4(const float* __restrict__ x,
                    const unsigned short* __restrict__ whQKV,
                    const unsigned short* __restrict__ whP,
                    const float* __restrict__ b_proj,
                    const float* __restrict__ biasT,
                    float* __restrict__ out)
{
    // Xs: f16 window input [tok 0..63][ch 0..127] stride 136 halves (272B,
    //     16B-aligned rows; word-stride 68 -> worst 2-way bank alias = free).
    // Osh: attention output exchange, same geometry.
    __shared__ __align__(16) unsigned short Xs[64 * 136];    // 17408 B
    __shared__ __align__(16) unsigned short Osh[64 * 136];   // 17408 B

    const int tid  = threadIdx.x;
    const int h    = tid >> 6;         // wave id == head
    const int lane = tid & 63;
    const int c    = lane & 15;
    const int g    = lane >> 4;

    const int blk  = blockIdx.x;
    const int b    = blk >> 6;
    const int wIdx = blk & 63;
    const int wh   = wIdx >> 3, ww = wIdx & 7;
    const int wtype = ((wh == 7) ? 2 : 0) | ((ww == 7) ? 1 : 0);

    auto tokAddr = [&](int tok) {      // tok must be < 49
        int rr = tok / 7, cc = tok - rr * 7;
        int sh = wh * 7 + rr + 3; if (sh >= HWD) sh -= HWD;
        int sw = ww * 7 + cc + 3; if (sw >= HWD) sw -= HWD;
        return ((b * HWD + sh) * HWD + sw) * 128;
    };

    // ---- stage X: coalesced (32 lanes cover one 512B token row), f32->f16
    for (int idx = tid; idx < 2048; idx += 256) {
        int tok = idx >> 5, ch4 = (idx & 31) << 2;
        uint2 wv = make_uint2(0u, 0u);                      // zero pad rows 49..63
        if (tok < 49) {
            const float4 v = *(const float4*)(x + tokAddr(tok) + ch4);
            wv = make_uint2(pkrtz(v.x, v.y), pkrtz(v.z, v.w));
        }
        *(uint2*)&Xs[tok * 136 + ch4] = wv;
    }
    __syncthreads();                   // barrier 1: X ready

    const int srcA  = c | ((lane & 16) << 1);  // lane (c, 2*(g&1))
    const int srcB  = srcA + 16;               // lane (c, 2*(g&1)+1)
    const bool hiSel = (lane & 32) != 0;       // g>>1 selects the tile-pair member

    // D->frag redistribution template (verified rounds 4/5):
    auto redist = [&](const unsigned pkLo[2], const unsigned pkHi[2], unsigned f[4]) {
        #pragma unroll
        for (int p = 0; p < 2; ++p) {
            unsigned lo0 = __shfl(pkLo[p], srcA);
            unsigned hi0 = __shfl(pkHi[p], srcA);
            f[p] = hiSel ? hi0 : lo0;
            unsigned lo1 = __shfl(pkLo[p], srcB);
            unsigned hi1 = __shfl(pkHi[p], srcB);
            f[2 + p] = hiSel ? hi1 : lo1;
        }
    };
    // weight A-frag loader: rows (base+c), k-slice g*8 (+32 per kstep)
    auto loadW = [&](const unsigned short* wbase, int rowBase, unsigned af[4][4]) {
        const unsigned short* wr = wbase + (rowBase + c) * 128 + g * 8;
        #pragma unroll
        for (int kk = 0; kk < 4; ++kk) {
            uint4 v = *(const uint4*)(wr + kk * 32);
            af[kk][0] = v.x; af[kk][1] = v.y; af[kk][2] = v.z; af[kk][3] = v.w;
        }
    };
    // X fragment (A- and B-frag content identical): tok-tile nt, from LDS
    auto xfrag = [&](int nt, unsigned xB[4][4]) {
        const unsigned short* xr = &Xs[(nt * 16 + c) * 136 + g * 8];
        #pragma unroll
        for (int kk = 0; kk < 4; ++kk) {
            uint4 v = *(const uint4*)(xr + kk * 32);
            xB[kk][0] = v.x; xB[kk][1] = v.y; xB[kk][2] = v.z; xB[kk][3] = v.w;
        }
    };

    // ================= phase A: own-head Q,K,V (no barrier) ========
    unsigned qB[4][4];                 // B[k=d][n=i] per i-tile nt
    unsigned kA[4][4];                 // A[m=j][k=d] per j-tile mt
    unsigned vA[2][2][4];              // A[m=d][k=j] per (d-tile, j-chunk)
    {
        unsigned pkP[2][4][2];
        // --- Q: mfma(Wq, X) -> D[qcol][tok]
        #pragma unroll
        for (int ql = 0; ql < 2; ++ql) {
            unsigned af[4][4];
            loadW(whQKV, 32 * h + 16 * ql, af);
            #pragma unroll
            for (int nt = 0; nt < 4; ++nt) {
                unsigned xB[4][4]; xfrag(nt, xB);
                f32x4 acc = {0.f, 0.f, 0.f, 0.f};
                #pragma unroll
                for (int kk = 0; kk < 4; ++kk) acc = mfma16(af[kk], xB[kk], acc);
                pkP[ql][nt][0] = pkrtz(acc[0], acc[1]);
                pkP[ql][nt][1] = pkrtz(acc[2], acc[3]);
            }
        }
        #pragma unroll
        for (int nt = 0; nt < 4; ++nt) redist(pkP[0][nt], pkP[1][nt], qB[nt]);

        // --- K: mfma(Wk, X) -> D[kcol][tok]
        #pragma unroll
        for (int kl = 0; kl < 2; ++kl) {
            unsigned af[4][4];
            loadW(whQKV, 128 + 32 * h + 16 * kl, af);
            #pragma unroll
            for (int mt = 0; mt < 4; ++mt) {
                unsigned xB[4][4]; xfrag(mt, xB);
                f32x4 acc = {0.f, 0.f, 0.f, 0.f};
                #pragma unroll
                for (int kk = 0; kk < 4; ++kk) acc = mfma16(af[kk], xB[kk], acc);
                pkP[kl][mt][0] = pkrtz(acc[0], acc[1]);
                pkP[kl][mt][1] = pkrtz(acc[2], acc[3]);
            }
        }
        #pragma unroll
        for (int mt = 0; mt < 4; ++mt) redist(pkP[0][mt], pkP[1][mt], kA[mt]);
    }
    // --- V: mfma(X, Wv) -> D[tok][d]; per-vl redist (pkV transient)
    #pragma unroll
    for (int vl = 0; vl < 2; ++vl) {
        unsigned bf[4][4];
        loadW(whQKV, 256 + 32 * h + 16 * vl, bf);
        unsigned pkV[4][2];
        #pragma unroll
        for (int mt = 0; mt < 4; ++mt) {
            unsigned xA[4][4]; xfrag(mt, xA);
            f32x4 acc = {0.f, 0.f, 0.f, 0.f};
            #pragma unroll
            for (int kk = 0; kk < 4; ++kk) acc = mfma16(xA[kk], bf[kk], acc);
            pkV[mt][0] = pkrtz(acc[0], acc[1]);
            pkV[mt][1] = pkrtz(acc[2], acc[3]);
        }
        #pragma unroll
        for (int kv = 0; kv < 2; ++kv)
            redist(pkV[2 * kv], pkV[2 * kv + 1], vA[vl][kv]);
    }

    // ================= attention (all in-register, per-i-tile fused) =======
    const float* bT = biasT + (wtype * 4 + h) * 4096;       // [i][j]
    f32x4 O[4][2];
    #pragma unroll
    for (int nt = 0; nt < 4; ++nt) {
        O[nt][0] = (f32x4){0.f, 0.f, 0.f, 0.f};
        O[nt][1] = (f32x4){0.f, 0.f, 0.f, 0.f};
    }

    #pragma unroll
    for (int nt = 0; nt < 4; ++nt) {
        f32x4 S[4];                    // S^T: lane j=16mt+4g+r, i=16nt+c
        #pragma unroll
        for (int mt = 0; mt < 4; ++mt) {
            float4 b4 = *(const float4*)&bT[(nt * 16 + c) * 64 + mt * 16 + 4 * g];
            f32x4 C = { b4.x, b4.y, b4.z, b4.w };           // bias as MFMA C-operand
            S[mt] = mfma16(kA[mt], qB[nt], C);
        }
        // softmax over j (16 in-lane + 2 butterflies)
        float m = -1e30f;
        #pragma unroll
        for (int mt = 0; mt < 4; ++mt)
            #pragma unroll
            for (int r = 0; r < 4; ++r) m = fmaxf(m, S[mt][r]);
        m = fmaxf(m, __shfl_xor(m, 16));
        m = fmaxf(m, __shfl_xor(m, 32));
        float s = 0.f;
        #pragma unroll
        for (int mt = 0; mt < 4; ++mt)
            #pragma unroll
            for (int r = 0; r < 4; ++r) { float e = __expf(S[mt][r] - m); S[mt][r] = e; s += e; }
        s += __shfl_xor(s, 16);
        s += __shfl_xor(s, 32);
        const float iv = 1.0f / s;
        // P -> B-frag via shuffles, PV mfma
        unsigned pk[4][2];
        #pragma unroll
        for (int mt = 0; mt < 4; ++mt) {
            pk[mt][0] = pkrtz(S[mt][0] * iv, S[mt][1] * iv);
            pk[mt][1] = pkrtz(S[mt][2] * iv, S[mt][3] * iv);
        }
        #pragma unroll
        for (int kk = 0; kk < 2; ++kk) {
            unsigned pB[4];
            redist(pk[2 * kk], pk[2 * kk + 1], pB);
            #pragma unroll
            for (int dn = 0; dn < 2; ++dn)
                O[nt][dn] = mfma16(vA[dn][kk], pB, O[nt][dn]);
        }
    }

    // O -> LDS: lane i = nt*16+c, d = 32h + 16dn + 4g..+3, stride 136 halves
    #pragma unroll
    for (int nt = 0; nt < 4; ++nt)
        #pragma unroll
        for (int dn = 0; dn < 2; ++dn)
            *(uint2*)&Osh[(nt * 16 + c) * 136 + 32 * h + 16 * dn + 4 * g] =
                make_uint2(pkrtz(O[nt][dn][0], O[nt][dn][1]),
                           pkrtz(O[nt][dn][2], O[nt][dn][3]));
    __syncthreads();                   // barrier 2: O ready

    // ================= out-proj: OUT = O @ Wproj^T + b =================
    int taddr[4];
    #pragma unroll
    for (int nt = 0; nt < 4; ++nt) {
        int tok = nt * 16 + c;
        taddr[nt] = (tok < 49) ? tokAddr(tok) : -1;
    }
    unsigned oB[4][4][4];              // B[k=d][n=i] from O[i][d]
    #pragma unroll
    for (int nt = 0; nt < 4; ++nt)
        #pragma unroll
        for (int kk = 0; kk < 4; ++kk) {
            uint4 v = *(const uint4*)&Osh[(nt * 16 + c) * 136 + kk * 32 + g * 8];
            oB[nt][kk][0] = v.x; oB[nt][kk][1] = v.y; oB[nt][kk][2] = v.z; oB[nt][kk][3] = v.w;
        }
    #pragma unroll
    for (int mi = 0; mi < 2; ++mi) {
        const int mt = 2 * h + mi;                          // out-col tile 0..7
        unsigned aW[4][4];
        loadW(whP, 16 * mt, aW);
        float4 bias4 = *(const float4*)(b_proj + mt * 16 + 4 * g);
        #pragma unroll
        for (int nt = 0; nt < 4; ++nt) {
            f32x4 acc = {0.f, 0.f, 0.f, 0.f};
            #pragma unroll
            for (int kk = 0; kk < 4; ++kk) acc = mfma16(aW[kk], oB[nt][kk], acc);
            if (taddr[nt] >= 0) {
                float4 o = make_float4(acc[0] + bias4.x, acc[1] + bias4.y,
                                       acc[2] + bias4.z, acc[3] + bias4.w);
                *(float4*)(out + taddr[nt] + mt * 16 + 4 * g) = o;
            }
        }
    }
}

extern "C" void kernel_launch(void* const* d_in, const int* in_sizes, int n_in,
                              void* d_out, int out_size, void* d_ws, size_t ws_size,
                              hipStream_t stream) {
    const float* x     = (const float*)d_in[0];
    const float* rpb   = (const float*)d_in[1];
    const float* wqkv  = (const float*)d_in[2];
    const float* wproj = (const float*)d_in[3];
    const float* bproj = (const float*)d_in[4];
    float* outp = (float*)d_out;

    unsigned short* whQKV = (unsigned short*)d_ws;          // 49152 halves
    unsigned short* whP   = whQKV + 49152;                  // 16384 halves
    float* biasT = (float*)(whP + 16384);                   // 65536 f32

    prep2<<<512, 256, 0, stream>>>(rpb, wqkv, wproj, whQKV, whP, biasT);
    swin_msa_mfma4<<<32 * 64, 256, 0, stream>>>(x, whQKV, whP, bproj, biasT, outp);
}

// Round 7
// 73.102 us; speedup vs baseline: 1.2711x; 1.0413x over previous
//
#include <hip/hip_runtime.h>

// Fused Swin shifted-window MSA, one workgroup (4 waves) per 7x7 window.
// Round 7: register-diet on the round-6 structure to kill residual scratch
// spills (round 6: WRITE 98MB vs 51MB output => ~46MB spill traffic).
//  - O-tile stored to LDS immediately after its nt iteration (32 -> 8 regs)
//  - P f16 pack materialized per-kk pair only (8 -> 4 regs)
// Peak attention live-set ~110 <= 128 (launch_bounds 256,4) -> no spills.

#define HWD 56
#define SCALE_Q 0.17677669529663687f   // 1/sqrt(32)

typedef _Float16 f16x8 __attribute__((ext_vector_type(8)));
typedef __fp16   h16x2 __attribute__((ext_vector_type(2)));   // cvt_pkrtz return type
typedef float    f32x4 __attribute__((ext_vector_type(4)));

__device__ __forceinline__ unsigned pkrtz(float a, float b) {
    union { h16x2 h; unsigned u; } r;
    r.h = __builtin_amdgcn_cvt_pkrtz(a, b);
    return r.u;
}

__device__ __forceinline__ f32x4 mfma16(const unsigned a[4], const unsigned b[4], f32x4 c) {
    union { unsigned u[4]; f16x8 h; } A, B;
    A.u[0] = a[0]; A.u[1] = a[1]; A.u[2] = a[2]; A.u[3] = a[3];
    B.u[0] = b[0]; B.u[1] = b[1]; B.u[2] = b[2]; B.u[3] = b[3];
    return __builtin_amdgcn_mfma_f32_16x16x32_f16(A.h, B.h, c, 0, 0, 0);
}

__device__ __forceinline__ unsigned short f16b(float v) {
    union { _Float16 h; unsigned short s; } cv; cv.h = (_Float16)v; return cv.s;
}

// whQKV: f16 [384][128] (rows 0..127 pre-scaled by 1/sqrt(hd))
// whP  : f16 [128][128]
// biasT: f32 [wtype][head][i][j]  (rel-pos bias + shift mask + key-pad mask)
__global__ void prep2(const float* __restrict__ rpb,
                      const float* __restrict__ w_qkv,
                      const float* __restrict__ w_proj,
                      unsigned short* __restrict__ whQKV,
                      unsigned short* __restrict__ whP,
                      float* __restrict__ biasT)
{
    int idx = blockIdx.x * 256 + threadIdx.x;               // 131072 total
    if (idx < 49152) {
        float v = w_qkv[idx];
        if (idx < 16384) v *= SCALE_Q;                      // q rows 0..127
        whQKV[idx] = f16b(v);
    } else if (idx < 65536) {
        int j = idx - 49152;
        whP[j] = f16b(w_proj[j]);
    } else {
        int k = idx - 65536;                                // 65536 bias elems
        int j = k & 63, i = (k >> 6) & 63, h = (k >> 12) & 3, t = k >> 14;
        float v;
        if (j >= 49)      v = -1e30f;                       // key padding
        else if (i >= 49) v = 0.f;                          // query padding (don't care)
        else {
            int ri = i / 7, ci = i % 7, rj = j / 7, cj = j % 7;
            int rel = (ri - rj + 6) * 13 + (ci - cj + 6);
            v = rpb[rel * 4 + h];
            int gi = ((t & 2) ? (ri < 4 ? 1 : 2) : 0) * 3 + ((t & 1) ? (ci < 4 ? 1 : 2) : 0);
            int gj = ((t & 2) ? (rj < 4 ? 1 : 2) : 0) * 3 + ((t & 1) ? (cj < 4 ? 1 : 2) : 0);
            if (gi != gj) v -= 100.f;
        }
        biasT[k] = v;
    }
}

__global__ __launch_bounds__(256, 4)
void swin_msa_mfma5(const float* __restrict__ x,
                    const unsigned short* __restrict__ whQKV,
                    const unsigned short* __restrict__ whP,
                    const float* __restrict__ b_proj,
                    const float* __restrict__ biasT,
                    float* __restrict__ out)
{
    // Xs: f16 window input [tok 0..63][ch 0..127] stride 136 halves.
    // Osh: attention output exchange, same geometry.
    __shared__ __align__(16) unsigned short Xs[64 * 136];    // 17408 B
    __shared__ __align__(16) unsigned short Osh[64 * 136];   // 17408 B

    const int tid  = threadIdx.x;
    const int h    = tid >> 6;         // wave id == head
    const int lane = tid & 63;
    const int c    = lane & 15;
    const int g    = lane >> 4;

    const int blk  = blockIdx.x;
    const int b    = blk >> 6;
    const int wIdx = blk & 63;
    const int wh   = wIdx >> 3, ww = wIdx & 7;
    const int wtype = ((wh == 7) ? 2 : 0) | ((ww == 7) ? 1 : 0);

    auto tokAddr = [&](int tok) {      // tok must be < 49
        int rr = tok / 7, cc = tok - rr * 7;
        int sh = wh * 7 + rr + 3; if (sh >= HWD) sh -= HWD;
        int sw = ww * 7 + cc + 3; if (sw >= HWD) sw -= HWD;
        return ((b * HWD + sh) * HWD + sw) * 128;
    };

    // ---- stage X: coalesced (32 lanes cover one 512B token row), f32->f16
    for (int idx = tid; idx < 2048; idx += 256) {
        int tok = idx >> 5, ch4 = (idx & 31) << 2;
        uint2 wv = make_uint2(0u, 0u);                      // zero pad rows 49..63
        if (tok < 49) {
            const float4 v = *(const float4*)(x + tokAddr(tok) + ch4);
            wv = make_uint2(pkrtz(v.x, v.y), pkrtz(v.z, v.w));
        }
        *(uint2*)&Xs[tok * 136 + ch4] = wv;
    }
    __syncthreads();                   // barrier 1: X ready

    const int srcA  = c | ((lane & 16) << 1);  // lane (c, 2*(g&1))
    const int srcB  = srcA + 16;               // lane (c, 2*(g&1)+1)
    const bool hiSel = (lane & 32) != 0;       // g>>1 selects the tile-pair member

    // D->frag redistribution template (verified rounds 4/5/6):
    auto redist = [&](const unsigned pkLo[2], const unsigned pkHi[2], unsigned f[4]) {
        #pragma unroll
        for (int p = 0; p < 2; ++p) {
            unsigned lo0 = __shfl(pkLo[p], srcA);
            unsigned hi0 = __shfl(pkHi[p], srcA);
            f[p] = hiSel ? hi0 : lo0;
            unsigned lo1 = __shfl(pkLo[p], srcB);
            unsigned hi1 = __shfl(pkHi[p], srcB);
            f[2 + p] = hiSel ? hi1 : lo1;
        }
    };
    // weight A-frag loader: rows (base+c), k-slice g*8 (+32 per kstep)
    auto loadW = [&](const unsigned short* wbase, int rowBase, unsigned af[4][4]) {
        const unsigned short* wr = wbase + (rowBase + c) * 128 + g * 8;
        #pragma unroll
        for (int kk = 0; kk < 4; ++kk) {
            uint4 v = *(const uint4*)(wr + kk * 32);
            af[kk][0] = v.x; af[kk][1] = v.y; af[kk][2] = v.z; af[kk][3] = v.w;
        }
    };
    // X fragment (A- and B-frag content identical): tok-tile nt, from LDS
    auto xfrag = [&](int nt, unsigned xB[4][4]) {
        const unsigned short* xr = &Xs[(nt * 16 + c) * 136 + g * 8];
        #pragma unroll
        for (int kk = 0; kk < 4; ++kk) {
            uint4 v = *(const uint4*)(xr + kk * 32);
            xB[kk][0] = v.x; xB[kk][1] = v.y; xB[kk][2] = v.z; xB[kk][3] = v.w;
        }
    };

    // ================= phase A: own-head Q,K,V (no barrier) ========
    unsigned qB[4][4];                 // B[k=d][n=i] per i-tile nt
    unsigned kA[4][4];                 // A[m=j][k=d] per j-tile mt
    unsigned vA[2][2][4];              // A[m=d][k=j] per (d-tile, j-chunk)
    {
        unsigned pkP[2][4][2];
        // --- Q: mfma(Wq, X) -> D[qcol][tok]
        #pragma unroll
        for (int ql = 0; ql < 2; ++ql) {
            unsigned af[4][4];
            loadW(whQKV, 32 * h + 16 * ql, af);
            #pragma unroll
            for (int nt = 0; nt < 4; ++nt) {
                unsigned xB[4][4]; xfrag(nt, xB);
                f32x4 acc = {0.f, 0.f, 0.f, 0.f};
                #pragma unroll
                for (int kk = 0; kk < 4; ++kk) acc = mfma16(af[kk], xB[kk], acc);
                pkP[ql][nt][0] = pkrtz(acc[0], acc[1]);
                pkP[ql][nt][1] = pkrtz(acc[2], acc[3]);
            }
        }
        #pragma unroll
        for (int nt = 0; nt < 4; ++nt) redist(pkP[0][nt], pkP[1][nt], qB[nt]);

        // --- K: mfma(Wk, X) -> D[kcol][tok]
        #pragma unroll
        for (int kl = 0; kl < 2; ++kl) {
            unsigned af[4][4];
            loadW(whQKV, 128 + 32 * h + 16 * kl, af);
            #pragma unroll
            for (int mt = 0; mt < 4; ++mt) {
                unsigned xB[4][4]; xfrag(mt, xB);
                f32x4 acc = {0.f, 0.f, 0.f, 0.f};
                #pragma unroll
                for (int kk = 0; kk < 4; ++kk) acc = mfma16(af[kk], xB[kk], acc);
                pkP[kl][mt][0] = pkrtz(acc[0], acc[1]);
                pkP[kl][mt][1] = pkrtz(acc[2], acc[3]);
            }
        }
        #pragma unroll
        for (int mt = 0; mt < 4; ++mt) redist(pkP[0][mt], pkP[1][mt], kA[mt]);
    }
    // --- V: mfma(X, Wv) -> D[tok][d]; per-vl redist (pkV transient)
    #pragma unroll
    for (int vl = 0; vl < 2; ++vl) {
        unsigned bf[4][4];
        loadW(whQKV, 256 + 32 * h + 16 * vl, bf);
        unsigned pkV[4][2];
        #pragma unroll
        for (int mt = 0; mt < 4; ++mt) {
            unsigned xA[4][4]; xfrag(mt, xA);
            f32x4 acc = {0.f, 0.f, 0.f, 0.f};
            #pragma unroll
            for (int kk = 0; kk < 4; ++kk) acc = mfma16(xA[kk], bf[kk], acc);
            pkV[mt][0] = pkrtz(acc[0], acc[1]);
            pkV[mt][1] = pkrtz(acc[2], acc[3]);
        }
        #pragma unroll
        for (int kv = 0; kv < 2; ++kv)
            redist(pkV[2 * kv], pkV[2 * kv + 1], vA[vl][kv]);
    }

    // ================= attention: per-i-tile fused, O stored per-tile ======
    const float* bT = biasT + (wtype * 4 + h) * 4096;       // [i][j]

    #pragma unroll
    for (int nt = 0; nt < 4; ++nt) {
        f32x4 S[4];                    // S^T: lane j=16mt+4g+r, i=16nt+c
        #pragma unroll
        for (int mt = 0; mt < 4; ++mt) {
            float4 b4 = *(const float4*)&bT[(nt * 16 + c) * 64 + mt * 16 + 4 * g];
            f32x4 C = { b4.x, b4.y, b4.z, b4.w };           // bias as MFMA C-operand
            S[mt] = mfma16(kA[mt], qB[nt], C);
        }
        // softmax over j (16 in-lane + 2 butterflies)
        float m = -1e30f;
        #pragma unroll
        for (int mt = 0; mt < 4; ++mt)
            #pragma unroll
            for (int r = 0; r < 4; ++r) m = fmaxf(m, S[mt][r]);
        m = fmaxf(m, __shfl_xor(m, 16));
        m = fmaxf(m, __shfl_xor(m, 32));
        float s = 0.f;
        #pragma unroll
        for (int mt = 0; mt < 4; ++mt)
            #pragma unroll
            for (int r = 0; r < 4; ++r) { float e = __expf(S[mt][r] - m); S[mt][r] = e; s += e; }
        s += __shfl_xor(s, 16);
        s += __shfl_xor(s, 32);
        const float iv = 1.0f / s;

        // PV: pack P per-kk pair only, redist -> B-frag, accumulate o0/o1
        f32x4 o0 = {0.f, 0.f, 0.f, 0.f};
        f32x4 o1 = {0.f, 0.f, 0.f, 0.f};
        #pragma unroll
        for (int kk = 0; kk < 2; ++kk) {
            unsigned pkLo[2], pkHi[2];
            pkLo[0] = pkrtz(S[2 * kk][0] * iv,     S[2 * kk][1] * iv);
            pkLo[1] = pkrtz(S[2 * kk][2] * iv,     S[2 * kk][3] * iv);
            pkHi[0] = pkrtz(S[2 * kk + 1][0] * iv, S[2 * kk + 1][1] * iv);
            pkHi[1] = pkrtz(S[2 * kk + 1][2] * iv, S[2 * kk + 1][3] * iv);
            unsigned pB[4];
            redist(pkLo, pkHi, pB);
            o0 = mfma16(vA[0][kk], pB, o0);
            o1 = mfma16(vA[1][kk], pB, o1);
        }
        // O-tile nt complete -> store now (frees regs, overlaps next nt)
        *(uint2*)&Osh[(nt * 16 + c) * 136 + 32 * h + 4 * g] =
            make_uint2(pkrtz(o0[0], o0[1]), pkrtz(o0[2], o0[3]));
        *(uint2*)&Osh[(nt * 16 + c) * 136 + 32 * h + 16 + 4 * g] =
            make_uint2(pkrtz(o1[0], o1[1]), pkrtz(o1[2], o1[3]));
    }
    __syncthreads();                   // barrier 2: O ready

    // ================= out-proj: OUT = O @ Wproj^T + b =================
    int taddr[4];
    #pragma unroll
    for (int nt = 0; nt < 4; ++nt) {
        int tok = nt * 16 + c;
        taddr[nt] = (tok < 49) ? tokAddr(tok) : -1;
    }
    unsigned oB[4][4][4];              // B[k=d][n=i] from O[i][d]
    #pragma unroll
    for (int nt = 0; nt < 4; ++nt)
        #pragma unroll
        for (int kk = 0; kk < 4; ++kk) {
            uint4 v = *(const uint4*)&Osh[(nt * 16 + c) * 136 + kk * 32 + g * 8];
            oB[nt][kk][0] = v.x; oB[nt][kk][1] = v.y; oB[nt][kk][2] = v.z; oB[nt][kk][3] = v.w;
        }
    #pragma unroll
    for (int mi = 0; mi < 2; ++mi) {
        const int mt = 2 * h + mi;                          // out-col tile 0..7
        unsigned aW[4][4];
        loadW(whP, 16 * mt, aW);
        float4 bias4 = *(const float4*)(b_proj + mt * 16 + 4 * g);
        #pragma unroll
        for (int nt = 0; nt < 4; ++nt) {
            f32x4 acc = {0.f, 0.f, 0.f, 0.f};
            #pragma unroll
            for (int kk = 0; kk < 4; ++kk) acc = mfma16(aW[kk], oB[nt][kk], acc);
            if (taddr[nt] >= 0) {
                float4 o = make_float4(acc[0] + bias4.x, acc[1] + bias4.y,
                                       acc[2] + bias4.z, acc[3] + bias4.w);
                *(float4*)(out + taddr[nt] + mt * 16 + 4 * g) = o;
            }
        }
    }
}

extern "C" void kernel_launch(void* const* d_in, const int* in_sizes, int n_in,
                              void* d_out, int out_size, void* d_ws, size_t ws_size,
                              hipStream_t stream) {
    const float* x     = (const float*)d_in[0];
    const float* rpb   = (const float*)d_in[1];
    const float* wqkv  = (const float*)d_in[2];
    const float* wproj = (const float*)d_in[3];
    const float* bproj = (const float*)d_in[4];
    float* outp = (float*)d_out;

    unsigned short* whQKV = (unsigned short*)d_ws;          // 49152 halves
    unsigned short* whP   = whQKV + 49152;                  // 16384 halves
    float* biasT = (float*)(whP + 16384);                   // 65536 f32

    prep2<<<512, 256, 0, stream>>>(rpb, wqkv, wproj, whQKV, whP, biasT);
    swin_msa_mfma5<<<32 * 64, 256, 0, stream>>>(x, whQKV, whP, bproj, biasT, outp);
}

// Round 8
// 68.949 us; speedup vs baseline: 1.3477x; 1.0602x over previous
//
#include <hip/hip_runtime.h>

// Fused Swin shifted-window MSA, one workgroup (4 waves) per 7x7 window.
// Round 8: single change vs round 7 — __launch_bounds__(256,3).
// Rationale: VGPR file = 512/SIMD, so (256,4) capped unified VGPR+AGPR at 128
// (compiler split 64 arch + 64 acc and spilled the f16 A/B fragments ->
// ~34MB scratch writes/dispatch, visible as WRITE_SIZE 85MB vs 51MB output).
// (256,3) raises the budget to ~170: live set ~130 fits, zero spills, and
// 12 waves/CU matches the ~12.5 we actually achieved under (256,4) anyway.

#define HWD 56
#define SCALE_Q 0.17677669529663687f   // 1/sqrt(32)

typedef _Float16 f16x8 __attribute__((ext_vector_type(8)));
typedef __fp16   h16x2 __attribute__((ext_vector_type(2)));   // cvt_pkrtz return type
typedef float    f32x4 __attribute__((ext_vector_type(4)));

__device__ __forceinline__ unsigned pkrtz(float a, float b) {
    union { h16x2 h; unsigned u; } r;
    r.h = __builtin_amdgcn_cvt_pkrtz(a, b);
    return r.u;
}

__device__ __forceinline__ f32x4 mfma16(const unsigned a[4], const unsigned b[4], f32x4 c) {
    union { unsigned u[4]; f16x8 h; } A, B;
    A.u[0] = a[0]; A.u[1] = a[1]; A.u[2] = a[2]; A.u[3] = a[3];
    B.u[0] = b[0]; B.u[1] = b[1]; B.u[2] = b[2]; B.u[3] = b[3];
    return __builtin_amdgcn_mfma_f32_16x16x32_f16(A.h, B.h, c, 0, 0, 0);
}

__device__ __forceinline__ unsigned short f16b(float v) {
    union { _Float16 h; unsigned short s; } cv; cv.h = (_Float16)v; return cv.s;
}

// whQKV: f16 [384][128] (rows 0..127 pre-scaled by 1/sqrt(hd))
// whP  : f16 [128][128]
// biasT: f32 [wtype][head][i][j]  (rel-pos bias + shift mask + key-pad mask)
__global__ void prep2(const float* __restrict__ rpb,
                      const float* __restrict__ w_qkv,
                      const float* __restrict__ w_proj,
                      unsigned short* __restrict__ whQKV,
                      unsigned short* __restrict__ whP,
                      float* __restrict__ biasT)
{
    int idx = blockIdx.x * 256 + threadIdx.x;               // 131072 total
    if (idx < 49152) {
        float v = w_qkv[idx];
        if (idx < 16384) v *= SCALE_Q;                      // q rows 0..127
        whQKV[idx] = f16b(v);
    } else if (idx < 65536) {
        int j = idx - 49152;
        whP[j] = f16b(w_proj[j]);
    } else {
        int k = idx - 65536;                                // 65536 bias elems
        int j = k & 63, i = (k >> 6) & 63, h = (k >> 12) & 3, t = k >> 14;
        float v;
        if (j >= 49)      v = -1e30f;                       // key padding
        else if (i >= 49) v = 0.f;                          // query padding (don't care)
        else {
            int ri = i / 7, ci = i % 7, rj = j / 7, cj = j % 7;
            int rel = (ri - rj + 6) * 13 + (ci - cj + 6);
            v = rpb[rel * 4 + h];
            int gi = ((t & 2) ? (ri < 4 ? 1 : 2) : 0) * 3 + ((t & 1) ? (ci < 4 ? 1 : 2) : 0);
            int gj = ((t & 2) ? (rj < 4 ? 1 : 2) : 0) * 3 + ((t & 1) ? (cj < 4 ? 1 : 2) : 0);
            if (gi != gj) v -= 100.f;
        }
        biasT[k] = v;
    }
}

__global__ __launch_bounds__(256, 3)
void swin_msa_mfma6(const float* __restrict__ x,
                    const unsigned short* __restrict__ whQKV,
                    const unsigned short* __restrict__ whP,
                    const float* __restrict__ b_proj,
                    const float* __restrict__ biasT,
                    float* __restrict__ out)
{
    // Xs: f16 window input [tok 0..63][ch 0..127] stride 136 halves.
    // Osh: attention output exchange, same geometry.
    __shared__ __align__(16) unsigned short Xs[64 * 136];    // 17408 B
    __shared__ __align__(16) unsigned short Osh[64 * 136];   // 17408 B

    const int tid  = threadIdx.x;
    const int h    = tid >> 6;         // wave id == head
    const int lane = tid & 63;
    const int c    = lane & 15;
    const int g    = lane >> 4;

    const int blk  = blockIdx.x;
    const int b    = blk >> 6;
    const int wIdx = blk & 63;
    const int wh   = wIdx >> 3, ww = wIdx & 7;
    const int wtype = ((wh == 7) ? 2 : 0) | ((ww == 7) ? 1 : 0);

    auto tokAddr = [&](int tok) {      // tok must be < 49
        int rr = tok / 7, cc = tok - rr * 7;
        int sh = wh * 7 + rr + 3; if (sh >= HWD) sh -= HWD;
        int sw = ww * 7 + cc + 3; if (sw >= HWD) sw -= HWD;
        return ((b * HWD + sh) * HWD + sw) * 128;
    };

    // ---- stage X: coalesced (32 lanes cover one 512B token row), f32->f16
    for (int idx = tid; idx < 2048; idx += 256) {
        int tok = idx >> 5, ch4 = (idx & 31) << 2;
        uint2 wv = make_uint2(0u, 0u);                      // zero pad rows 49..63
        if (tok < 49) {
            const float4 v = *(const float4*)(x + tokAddr(tok) + ch4);
            wv = make_uint2(pkrtz(v.x, v.y), pkrtz(v.z, v.w));
        }
        *(uint2*)&Xs[tok * 136 + ch4] = wv;
    }
    __syncthreads();                   // barrier 1: X ready

    const int srcA  = c | ((lane & 16) << 1);  // lane (c, 2*(g&1))
    const int srcB  = srcA + 16;               // lane (c, 2*(g&1)+1)
    const bool hiSel = (lane & 32) != 0;       // g>>1 selects the tile-pair member

    // D->frag redistribution template (verified rounds 4/5/6/7):
    auto redist = [&](const unsigned pkLo[2], const unsigned pkHi[2], unsigned f[4]) {
        #pragma unroll
        for (int p = 0; p < 2; ++p) {
            unsigned lo0 = __shfl(pkLo[p], srcA);
            unsigned hi0 = __shfl(pkHi[p], srcA);
            f[p] = hiSel ? hi0 : lo0;
            unsigned lo1 = __shfl(pkLo[p], srcB);
            unsigned hi1 = __shfl(pkHi[p], srcB);
            f[2 + p] = hiSel ? hi1 : lo1;
        }
    };
    // weight A-frag loader: rows (base+c), k-slice g*8 (+32 per kstep)
    auto loadW = [&](const unsigned short* wbase, int rowBase, unsigned af[4][4]) {
        const unsigned short* wr = wbase + (rowBase + c) * 128 + g * 8;
        #pragma unroll
        for (int kk = 0; kk < 4; ++kk) {
            uint4 v = *(const uint4*)(wr + kk * 32);
            af[kk][0] = v.x; af[kk][1] = v.y; af[kk][2] = v.z; af[kk][3] = v.w;
        }
    };
    // X fragment (A- and B-frag content identical): tok-tile nt, from LDS
    auto xfrag = [&](int nt, unsigned xB[4][4]) {
        const unsigned short* xr = &Xs[(nt * 16 + c) * 136 + g * 8];
        #pragma unroll
        for (int kk = 0; kk < 4; ++kk) {
            uint4 v = *(const uint4*)(xr + kk * 32);
            xB[kk][0] = v.x; xB[kk][1] = v.y; xB[kk][2] = v.z; xB[kk][3] = v.w;
        }
    };

    // ================= phase A: own-head Q,K,V (no barrier) ========
    unsigned qB[4][4];                 // B[k=d][n=i] per i-tile nt
    unsigned kA[4][4];                 // A[m=j][k=d] per j-tile mt
    unsigned vA[2][2][4];              // A[m=d][k=j] per (d-tile, j-chunk)
    {
        unsigned pkP[2][4][2];
        // --- Q: mfma(Wq, X) -> D[qcol][tok]
        #pragma unroll
        for (int ql = 0; ql < 2; ++ql) {
            unsigned af[4][4];
            loadW(whQKV, 32 * h + 16 * ql, af);
            #pragma unroll
            for (int nt = 0; nt < 4; ++nt) {
                unsigned xB[4][4]; xfrag(nt, xB);
                f32x4 acc = {0.f, 0.f, 0.f, 0.f};
                #pragma unroll
                for (int kk = 0; kk < 4; ++kk) acc = mfma16(af[kk], xB[kk], acc);
                pkP[ql][nt][0] = pkrtz(acc[0], acc[1]);
                pkP[ql][nt][1] = pkrtz(acc[2], acc[3]);
            }
        }
        #pragma unroll
        for (int nt = 0; nt < 4; ++nt) redist(pkP[0][nt], pkP[1][nt], qB[nt]);

        // --- K: mfma(Wk, X) -> D[kcol][tok]
        #pragma unroll
        for (int kl = 0; kl < 2; ++kl) {
            unsigned af[4][4];
            loadW(whQKV, 128 + 32 * h + 16 * kl, af);
            #pragma unroll
            for (int mt = 0; mt < 4; ++mt) {
                unsigned xB[4][4]; xfrag(mt, xB);
                f32x4 acc = {0.f, 0.f, 0.f, 0.f};
                #pragma unroll
                for (int kk = 0; kk < 4; ++kk) acc = mfma16(af[kk], xB[kk], acc);
                pkP[kl][mt][0] = pkrtz(acc[0], acc[1]);
                pkP[kl][mt][1] = pkrtz(acc[2], acc[3]);
            }
        }
        #pragma unroll
        for (int mt = 0; mt < 4; ++mt) redist(pkP[0][mt], pkP[1][mt], kA[mt]);
    }
    // --- V: mfma(X, Wv) -> D[tok][d]; per-vl redist (pkV transient)
    #pragma unroll
    for (int vl = 0; vl < 2; ++vl) {
        unsigned bf[4][4];
        loadW(whQKV, 256 + 32 * h + 16 * vl, bf);
        unsigned pkV[4][2];
        #pragma unroll
        for (int mt = 0; mt < 4; ++mt) {
            unsigned xA[4][4]; xfrag(mt, xA);
            f32x4 acc = {0.f, 0.f, 0.f, 0.f};
            #pragma unroll
            for (int kk = 0; kk < 4; ++kk) acc = mfma16(xA[kk], bf[kk], acc);
            pkV[mt][0] = pkrtz(acc[0], acc[1]);
            pkV[mt][1] = pkrtz(acc[2], acc[3]);
        }
        #pragma unroll
        for (int kv = 0; kv < 2; ++kv)
            redist(pkV[2 * kv], pkV[2 * kv + 1], vA[vl][kv]);
    }

    // ================= attention: per-i-tile fused, O stored per-tile ======
    const float* bT = biasT + (wtype * 4 + h) * 4096;       // [i][j]

    #pragma unroll
    for (int nt = 0; nt < 4; ++nt) {
        f32x4 S[4];                    // S^T: lane j=16mt+4g+r, i=16nt+c
        #pragma unroll
        for (int mt = 0; mt < 4; ++mt) {
            float4 b4 = *(const float4*)&bT[(nt * 16 + c) * 64 + mt * 16 + 4 * g];
            f32x4 C = { b4.x, b4.y, b4.z, b4.w };           // bias as MFMA C-operand
            S[mt] = mfma16(kA[mt], qB[nt], C);
        }
        // softmax over j (16 in-lane + 2 butterflies)
        float m = -1e30f;
        #pragma unroll
        for (int mt = 0; mt < 4; ++mt)
            #pragma unroll
            for (int r = 0; r < 4; ++r) m = fmaxf(m, S[mt][r]);
        m = fmaxf(m, __shfl_xor(m, 16));
        m = fmaxf(m, __shfl_xor(m, 32));
        float s = 0.f;
        #pragma unroll
        for (int mt = 0; mt < 4; ++mt)
            #pragma unroll
            for (int r = 0; r < 4; ++r) { float e = __expf(S[mt][r] - m); S[mt][r] = e; s += e; }
        s += __shfl_xor(s, 16);
        s += __shfl_xor(s, 32);
        const float iv = 1.0f / s;

        // PV: pack P per-kk pair only, redist -> B-frag, accumulate o0/o1
        f32x4 o0 = {0.f, 0.f, 0.f, 0.f};
        f32x4 o1 = {0.f, 0.f, 0.f, 0.f};
        #pragma unroll
        for (int kk = 0; kk < 2; ++kk) {
            unsigned pkLo[2], pkHi[2];
            pkLo[0] = pkrtz(S[2 * kk][0] * iv,     S[2 * kk][1] * iv);
            pkLo[1] = pkrtz(S[2 * kk][2] * iv,     S[2 * kk][3] * iv);
            pkHi[0] = pkrtz(S[2 * kk + 1][0] * iv, S[2 * kk + 1][1] * iv);
            pkHi[1] = pkrtz(S[2 * kk + 1][2] * iv, S[2 * kk + 1][3] * iv);
            unsigned pB[4];
            redist(pkLo, pkHi, pB);
            o0 = mfma16(vA[0][kk], pB, o0);
            o1 = mfma16(vA[1][kk], pB, o1);
        }
        // O-tile nt complete -> store now (frees regs, overlaps next nt)
        *(uint2*)&Osh[(nt * 16 + c) * 136 + 32 * h + 4 * g] =
            make_uint2(pkrtz(o0[0], o0[1]), pkrtz(o0[2], o0[3]));
        *(uint2*)&Osh[(nt * 16 + c) * 136 + 32 * h + 16 + 4 * g] =
            make_uint2(pkrtz(o1[0], o1[1]), pkrtz(o1[2], o1[3]));
    }
    __syncthreads();                   // barrier 2: O ready

    // ================= out-proj: OUT = O @ Wproj^T + b =================
    int taddr[4];
    #pragma unroll
    for (int nt = 0; nt < 4; ++nt) {
        int tok = nt * 16 + c;
        taddr[nt] = (tok < 49) ? tokAddr(tok) : -1;
    }
    unsigned oB[4][4][4];              // B[k=d][n=i] from O[i][d]
    #pragma unroll
    for (int nt = 0; nt < 4; ++nt)
        #pragma unroll
        for (int kk = 0; kk < 4; ++kk) {
            uint4 v = *(const uint4*)&Osh[(nt * 16 + c) * 136 + kk * 32 + g * 8];
            oB[nt][kk][0] = v.x; oB[nt][kk][1] = v.y; oB[nt][kk][2] = v.z; oB[nt][kk][3] = v.w;
        }
    #pragma unroll
    for (int mi = 0; mi < 2; ++mi) {
        const int mt = 2 * h + mi;                          // out-col tile 0..7
        unsigned aW[4][4];
        loadW(whP, 16 * mt, aW);
        float4 bias4 = *(const float4*)(b_proj + mt * 16 + 4 * g);
        #pragma unroll
        for (int nt = 0; nt < 4; ++nt) {
            f32x4 acc = {0.f, 0.f, 0.f, 0.f};
            #pragma unroll
            for (int kk = 0; kk < 4; ++kk) acc = mfma16(aW[kk], oB[nt][kk], acc);
            if (taddr[nt] >= 0) {
                float4 o = make_float4(acc[0] + bias4.x, acc[1] + bias4.y,
                                       acc[2] + bias4.z, acc[3] + bias4.w);
                *(float4*)(out + taddr[nt] + mt * 16 + 4 * g) = o;
            }
        }
    }
}

extern "C" void kernel_launch(void* const* d_in, const int* in_sizes, int n_in,
                              void* d_out, int out_size, void* d_ws, size_t ws_size,
                              hipStream_t stream) {
    const float* x     = (const float*)d_in[0];
    const float* rpb   = (const float*)d_in[1];
    const float* wqkv  = (const float*)d_in[2];
    const float* wproj = (const float*)d_in[3];
    const float* bproj = (const float*)d_in[4];
    float* outp = (float*)d_out;

    unsigned short* whQKV = (unsigned short*)d_ws;          // 49152 halves
    unsigned short* whP   = whQKV + 49152;                  // 16384 halves
    float* biasT = (float*)(whP + 16384);                   // 65536 f32

    prep2<<<512, 256, 0, stream>>>(rpb, wqkv, wproj, whQKV, whP, biasT);
    swin_msa_mfma6<<<32 * 64, 256, 0, stream>>>(x, whQKV, whP, bproj, biasT, outp);
}